// Round 2
// baseline (48.090 us; speedup 1.0000x reference)
//
#include <hip/hip_runtime.h>
#include <math.h>

// Canny NMS magnitude extractor, fully fused, occupancy-optimized.
// x: [16,3,512,512] f32 -> out: [16,3,512,512] f32

#define HH 512
#define WW 512
#define NB 16
#define TH 32          // output tile rows
#define TW 32          // output tile cols
#define GH 40          // gray tile rows (TH + 2*4)
#define GW 40          // gray tile cols
#define GS 41          // gray LDS row stride (odd -> bank spread)
#define BH 36          // blur tile rows (TH + 2*2)
#define BW 36          // blur tile cols
#define BS 37          // blur LDS row stride
#define MH 34          // mag tile rows (TH + 2*1)
#define MW 34          // mag tile cols
// mag overlays sG with stride GS (34*41 = 1394 <= 40*41 = 1640)

__device__ __forceinline__ int reflect_i(int i, int n) {
    // numpy 'reflect' (no edge repeat), valid for pad <= n-1
    if (i < 0) i = -i;
    if (i >= n) i = 2 * n - 2 - i;
    return i;
}

__global__ __launch_bounds__(256, 8)
void canny_fused_kernel(const float* __restrict__ in, float* __restrict__ out) {
    const int tx0 = blockIdx.x * TW;
    const int ty0 = blockIdx.y * TH;
    const int b   = blockIdx.z;
    const int tid = threadIdx.x;

    __shared__ float sG[GH * GS];   // gray tile; reused as mag tile
    __shared__ float sB[BH * BS];   // blur tile
    float* sMag = sG;

    // Gaussian 5x5 weights exactly as the reference (f32 expf, f32-sum normalize).
    // All compile-time constants -> folded, no VGPR cost.
    float g1[5];
    {
        float s = 0.f;
        #pragma unroll
        for (int i = 0; i < 5; ++i) {
            float a = (float)i - 2.0f;
            g1[i] = expf(-0.5f * a * a);
            s += g1[i];
        }
        #pragma unroll
        for (int i = 0; i < 5; ++i) g1[i] = g1[i] / s;
    }
    float w2d[25];
    #pragma unroll
    for (int j = 0; j < 5; ++j)
        #pragma unroll
        for (int i = 0; i < 5; ++i)
            w2d[j * 5 + i] = g1[j] * g1[i];

    const float* inb = in + (size_t)b * 3 * HH * WW;

    // -------- Phase 1: grayscale -> sG, reflect-mapped, raw coords [ty0-4, ty0+35]
    #pragma unroll
    for (int k = 0; k < (GH * GW + 255) / 256; ++k) {
        int s = tid + k * 256;
        if (s < GH * GW) {
            int j = s / GW, i = s - j * GW;
            int y = reflect_i(ty0 - 4 + j, HH);
            int x = reflect_i(tx0 - 4 + i, WW);
            const float* p = inb + y * WW + x;
            sG[j * GS + i] = p[0] * 0.299f + p[HH * WW] * 0.587f + p[2 * HH * WW] * 0.114f;
        }
    }
    __syncthreads();

    // -------- Phase 2: 5x5 gaussian blur at CLAMPED coords (sobel's replicate pad)
    #pragma unroll
    for (int k = 0; k < (BH * BW + 255) / 256; ++k) {
        int s = tid + k * 256;
        if (s < BH * BW) {
            int j = s / BW, i = s - j * BW;
            int yc = min(max(ty0 - 2 + j, 0), HH - 1);
            int xc = min(max(tx0 - 2 + i, 0), WW - 1);
            int lj = yc - (ty0 - 4);   // gray-tile row
            int li = xc - (tx0 - 4);
            float acc = 0.f;
            #pragma unroll
            for (int ky = 0; ky < 5; ++ky)
                #pragma unroll
                for (int kx = 0; kx < 5; ++kx)
                    acc += w2d[ky * 5 + kx] * sG[(lj + ky - 2) * GS + (li + kx - 2)];
            sB[j * BS + i] = acc;
        }
    }
    __syncthreads();

    // -------- Phase 3: sobel magnitude, raw coords [ty0-1, ty0+32]; 0 outside image.
    // Overwrites sG region (gray dead; phase reads only sB).
    #pragma unroll
    for (int k = 0; k < (MH * MW + 255) / 256; ++k) {
        int s = tid + k * 256;
        if (s < MH * MW) {
            int j = s / MW, i = s - j * MW;
            int y = ty0 - 1 + j;
            int x = tx0 - 1 + i;
            float m = 0.f;
            if (y >= 0 && y < HH && x >= 0 && x < WW) {
                int lj = y - (ty0 - 2);   // blur-tile row
                int li = x - (tx0 - 2);
                float b00 = sB[(lj - 1) * BS + (li - 1)];
                float b01 = sB[(lj - 1) * BS + li];
                float b02 = sB[(lj - 1) * BS + (li + 1)];
                float b10 = sB[lj * BS + (li - 1)];
                float b12 = sB[lj * BS + (li + 1)];
                float b20 = sB[(lj + 1) * BS + (li - 1)];
                float b21 = sB[(lj + 1) * BS + li];
                float b22 = sB[(lj + 1) * BS + (li + 1)];
                float gx = ((((-b00 + b02) - 2.f * b10) + 2.f * b12) - b20) + b22;
                float gy = ((((-b00 - 2.f * b01) - b02) + b20) + 2.f * b21) + b22;
                m = sqrtf(gx * gx + gy * gy + 1e-6f);
            }
            sMag[j * GS + i] = m;
        }
    }
    __syncthreads();

    // -------- Phase 4: angle bin + NMS + clip + write x3 channels (1024 = 4*256 exact)
    #pragma unroll
    for (int k = 0; k < (TH * TW) / 256; ++k) {
        int s = tid + k * 256;
        int j = s >> 5, i = s & 31;
        int y = ty0 + j, x = tx0 + i;
        int lj = j + 2, li = i + 2;   // blur-tile coords of (y,x)
        float b00 = sB[(lj - 1) * BS + (li - 1)];
        float b01 = sB[(lj - 1) * BS + li];
        float b02 = sB[(lj - 1) * BS + (li + 1)];
        float b10 = sB[lj * BS + (li - 1)];
        float b12 = sB[lj * BS + (li + 1)];
        float b20 = sB[(lj + 1) * BS + (li - 1)];
        float b21 = sB[(lj + 1) * BS + li];
        float b22 = sB[(lj + 1) * BS + (li + 1)];
        float gx = ((((-b00 + b02) - 2.f * b10) + 2.f * b12) - b20) + b22;
        float gy = ((((-b00 - 2.f * b01) - b02) + b20) + 2.f * b21) + b22;

        // ang_bin = round(degrees(atan2(gy,gx))/45), round-half-even like jnp.round
        float t = atan2f(gy, gx) * 57.29577951308232f;
        t = t / 45.0f;
        int bin = (int)rintf(t);
        int pos = (bin + 8) & 7;      // jnp.mod(bin, 8)

        // offsets[(i+4)%8] == -offsets[i]; (dy+1),(dx+1) packed 2 bits/direction.
        int dyp = ((425   >> (2 * pos)) & 3) - 1;
        int dxp = ((36890 >> (2 * pos)) & 3) - 1;

        float mc     = sMag[(j + 1) * GS + (i + 1)];
        float cs_pos = mc - sMag[(j + 1 + dyp) * GS + (i + 1 + dxp)];
        float cs_neg = mc - sMag[(j + 1 - dyp) * GS + (i + 1 - dxp)];
        float v = (fminf(cs_pos, cs_neg) > 0.0f) ? fminf(mc, 1.0f) : 0.0f;

        float* op = out + ((size_t)(b * 3) * HH + y) * WW + x;
        op[0] = v;
        op[(size_t)HH * WW] = v;
        op[(size_t)2 * HH * WW] = v;
    }
}

extern "C" void kernel_launch(void* const* d_in, const int* in_sizes, int n_in,
                              void* d_out, int out_size, void* d_ws, size_t ws_size,
                              hipStream_t stream) {
    const float* x = (const float*)d_in[0];
    float* out = (float*)d_out;
    dim3 grid(WW / TW, HH / TH, NB);
    dim3 block(256);
    hipLaunchKernelGGL(canny_fused_kernel, grid, block, 0, stream, x, out);
}

// Round 3
// 40.141 us; speedup vs baseline: 1.1980x; 1.1980x over previous
//
#include <hip/hip_runtime.h>
#include <math.h>

// Canny NMS magnitude extractor, fused + separable + vectorized.
// x: [16,3,512,512] f32 -> out: [16,3,512,512] f32

#define HH 512
#define WW 512
#define NB 16
#define TH 32            // output tile rows (y)
#define TW 64            // output tile cols (x)
// gray tile: 40 rows (y: ty0-4..ty0+35) x 72 cols (x: tx0-4..tx0+67), stride 76
#define GH 40
#define GW 72
#define GS 76
// htmp (horizontal blur): 40 rows x 68 cols (x: tx0-2..tx0+65), stride 68
#define HS 68
// blur: 36 rows (y: ty0-2..ty0+33) x 68 cols, stride 68
#define BH 36
#define BS 68
// mag: 34 rows (y: ty0-1..ty0+32) x 68 cols (x: tx0-1+c), overlays gray
// flags: 34 x 68 u32, overlays htmp

__device__ __forceinline__ int reflect_i(int i, int n) {
    if (i < 0) i = -i;
    if (i >= n) i = 2 * n - 2 - i;
    return i;
}

__global__ __launch_bounds__(256, 4)
void canny_fused_kernel(const float* __restrict__ in, float* __restrict__ out) {
    const int tx0 = blockIdx.x * TW;
    const int ty0 = blockIdx.y * TH;
    const int b   = blockIdx.z;
    const int tid = threadIdx.x;

    __shared__ float sPool[8208];          // 32832 B
    float*    sG = sPool;                  // 40*76 = 3040 floats
    float*    sH = sPool + 3040;           // 40*68 = 2720 floats
    float*    sB = sPool + 5760;           // 36*68 = 2448 floats
    float*    sM = sPool;                  // mag overlays gray (34*68 <= 3040)
    unsigned* sF = (unsigned*)(sPool + 3040); // flags overlay htmp (34*68 <= 2720)

    // Gaussian weights exactly as reference (f32 expf, f32-sum normalize)
    float g1[5];
    {
        float s = 0.f;
        #pragma unroll
        for (int i = 0; i < 5; ++i) {
            float a = (float)i - 2.0f;
            g1[i] = expf(-0.5f * a * a);
            s += g1[i];
        }
        #pragma unroll
        for (int i = 0; i < 5; ++i) g1[i] = g1[i] / s;
    }

    const float* inb = in + (size_t)b * 3 * HH * WW;

    // ---- P1: grayscale -> sG (reflect-mapped), float4 per thread -----------
    #pragma unroll
    for (int k = 0; k < 3; ++k) {
        int s = tid + k * 256;
        if (s < GH * (GW / 4)) {                 // 40*18 = 720
            int j = s / 18, q = s - j * 18;
            int y = reflect_i(ty0 - 4 + j, HH);
            int xs = tx0 - 4 + 4 * q;
            const float* p = inb + (size_t)y * WW;
            float4 gr;
            if (xs >= 0 && xs + 3 < WW) {
                float4 r = *(const float4*)(p + xs);
                float4 g = *(const float4*)(p + xs + HH * WW);
                float4 bl = *(const float4*)(p + xs + 2 * HH * WW);
                gr.x = r.x * 0.299f + g.x * 0.587f + bl.x * 0.114f;
                gr.y = r.y * 0.299f + g.y * 0.587f + bl.y * 0.114f;
                gr.z = r.z * 0.299f + g.z * 0.587f + bl.z * 0.114f;
                gr.w = r.w * 0.299f + g.w * 0.587f + bl.w * 0.114f;
            } else {
                float t[4];
                #pragma unroll
                for (int e = 0; e < 4; ++e) {
                    int xm = reflect_i(xs + e, WW);
                    t[e] = p[xm] * 0.299f + p[xm + HH * WW] * 0.587f
                         + p[xm + 2 * HH * WW] * 0.114f;
                }
                gr.x = t[0]; gr.y = t[1]; gr.z = t[2]; gr.w = t[3];
            }
            *(float4*)(sG + j * GS + 4 * q) = gr;
        }
    }
    __syncthreads();

    // ---- P2: horizontal gaussian, 4 outputs/thread -------------------------
    #pragma unroll
    for (int k = 0; k < 3; ++k) {
        int s = tid + k * 256;
        if (s < GH * 17) {                        // 680
            int j = s / 17, q = s - j * 17;
            int c0 = 4 * q;
            float4 a = *(const float4*)(sG + j * GS + c0);
            float4 bq = *(const float4*)(sG + j * GS + c0 + 4);
            float v0 = a.x, v1 = a.y, v2 = a.z, v3 = a.w;
            float v4 = bq.x, v5 = bq.y, v6 = bq.z, v7 = bq.w;
            float4 o;
            o.x = g1[0]*v0 + g1[1]*v1 + g1[2]*v2 + g1[3]*v3 + g1[4]*v4;
            o.y = g1[0]*v1 + g1[1]*v2 + g1[2]*v3 + g1[3]*v4 + g1[4]*v5;
            o.z = g1[0]*v2 + g1[1]*v3 + g1[2]*v4 + g1[3]*v5 + g1[4]*v6;
            o.w = g1[0]*v3 + g1[1]*v4 + g1[2]*v5 + g1[3]*v6 + g1[4]*v7;
            *(float4*)(sH + j * HS + c0) = o;
        }
    }
    __syncthreads();

    // ---- edge fixup: sobel replicate pad in x (blur(x<0)=blur(0) etc.) -----
    if (tx0 == 0) {
        if (tid < GH) {
            float v = sH[tid * HS + 2];
            sH[tid * HS + 0] = v;
            sH[tid * HS + 1] = v;
        }
        __syncthreads();
    }
    if (tx0 == WW - TW) {
        if (tid < GH) {
            float v = sH[tid * HS + 65];
            sH[tid * HS + 66] = v;
            sH[tid * HS + 67] = v;
        }
        __syncthreads();
    }

    // ---- P3: vertical gaussian (center-y clamped -> replicate pad in y) ----
    #pragma unroll
    for (int k = 0; k < 3; ++k) {
        int s = tid + k * 256;
        if (s < BH * 17) {                        // 612
            int r = s / 17, q = s - r * 17;
            int c0 = 4 * q;
            int yc = min(max(ty0 - 2 + r, 0), HH - 1);
            int rb = yc - ty0 + 2;                // htmp row base (taps rb..rb+4)
            float4 o = make_float4(0.f, 0.f, 0.f, 0.f);
            #pragma unroll
            for (int t = 0; t < 5; ++t) {
                float4 rw = *(const float4*)(sH + (rb + t) * HS + c0);
                o.x += g1[t] * rw.x;
                o.y += g1[t] * rw.y;
                o.z += g1[t] * rw.z;
                o.w += g1[t] * rw.w;
            }
            *(float4*)(sB + r * BS + c0) = o;
        }
    }
    __syncthreads();

    // ---- P4: sobel magnitude + direction flags ----------------------------
    #pragma unroll
    for (int k = 0; k < 3; ++k) {
        int s = tid + k * 256;
        if (s < 34 * 17) {                        // 578
            int m = s / 17, q = s - m * 17;
            int c0 = 4 * q;
            int c4 = (q == 16) ? 64 : c0 + 4;     // clamp (cols 66,67 unused)
            float R[3][8];
            #pragma unroll
            for (int r = 0; r < 3; ++r) {
                float4 a = *(const float4*)(sB + (m + r) * BS + c0);
                float4 bb = *(const float4*)(sB + (m + r) * BS + c4);
                R[r][0] = a.x;  R[r][1] = a.y;  R[r][2] = a.z;  R[r][3] = a.w;
                R[r][4] = bb.x; R[r][5] = bb.y; R[r][6] = bb.z; R[r][7] = bb.w;
            }
            int y = ty0 - 1 + m;
            bool yin = (y >= 0) && (y < HH);
            float mg[4]; unsigned fl[4];
            #pragma unroll
            for (int li = 0; li < 4; ++li) {
                float b00 = R[0][li], b01 = R[0][li+1], b02 = R[0][li+2];
                float b10 = R[1][li],                   b12 = R[1][li+2];
                float b20 = R[2][li], b21 = R[2][li+1], b22 = R[2][li+2];
                float gx = ((((-b00 + b02) - 2.f * b10) + 2.f * b12) - b20) + b22;
                float gy = ((((-b00 - 2.f * b01) - b02) + b20) + 2.f * b21) + b22;
                int x = tx0 - 1 + c0 + li;
                bool inimg = yin && (x >= 0) && (x < WW);
                mg[li] = inimg ? sqrtf(gx * gx + gy * gy + 1e-6f) : 0.0f;
                float adx = fabsf(gx), ady = fabsf(gy);
                unsigned f = 0;
                f |= (ady <= 0.41421356237309503f * adx) ? 1u : 0u;  // horizontal
                f |= (ady >= 2.414213562373095f  * adx) ? 2u : 0u;   // vertical
                f |= (gy >= 0.f) ? 4u : 0u;
                f |= (gx >= 0.f) ? 8u : 0u;
                fl[li] = f;
            }
            float4 mv; mv.x = mg[0]; mv.y = mg[1]; mv.z = mg[2]; mv.w = mg[3];
            uint4 fv; fv.x = fl[0]; fv.y = fl[1]; fv.z = fl[2]; fv.w = fl[3];
            *(float4*)(sM + m * 68 + c0) = mv;
            *(uint4*)(sF + m * 68 + c0) = fv;
        }
    }
    __syncthreads();

    // ---- P5: NMS select + clip + store x3 channels ------------------------
    #pragma unroll
    for (int k = 0; k < 2; ++k) {
        int s = tid + k * 256;                    // 512 exact
        int j = s >> 4, q = s & 15;
        int i0 = 4 * q;
        float W[3][6];
        #pragma unroll
        for (int r = 0; r < 3; ++r) {
            float4 a = *(const float4*)(sM + (j + r) * 68 + i0);
            float2 bb = *(const float2*)(sM + (j + r) * 68 + i0 + 4);
            W[r][0] = a.x; W[r][1] = a.y; W[r][2] = a.z; W[r][3] = a.w;
            W[r][4] = bb.x; W[r][5] = bb.y;
        }
        uint4 fa = *(const uint4*)(sF + (j + 1) * 68 + i0);
        unsigned fb = *(const unsigned*)(sF + (j + 1) * 68 + i0 + 4);
        unsigned F[4] = {fa.y, fa.z, fa.w, fb};

        float o[4];
        #pragma unroll
        for (int li = 0; li < 4; ++li) {
            float mc = W[1][li + 1];
            unsigned f = F[li];
            bool h  = (f & 1u) != 0u;
            bool v  = (f & 2u) != 0u;
            bool sy = (f & 4u) != 0u;
            bool sx = (f & 8u) != 0u;
            float p0 = v ? W[0][li+1] : (sx ? W[0][li+2] : W[0][li]);
            float p1 = v ? W[1][li+1] : (sx ? W[1][li+2] : W[1][li]);
            float p2 = v ? W[2][li+1] : (sx ? W[2][li+2] : W[2][li]);
            float pv = h ? p1 : (sy ? p2 : p0);
            float n0 = v ? W[0][li+1] : (sx ? W[0][li] : W[0][li+2]);
            float n1 = v ? W[1][li+1] : (sx ? W[1][li] : W[1][li+2]);
            float n2 = v ? W[2][li+1] : (sx ? W[2][li] : W[2][li+2]);
            float nv = h ? n1 : (sy ? n0 : n2);
            o[li] = (mc > fmaxf(pv, nv)) ? fminf(mc, 1.0f) : 0.0f;
        }
        float4 ov; ov.x = o[0]; ov.y = o[1]; ov.z = o[2]; ov.w = o[3];
        int y = ty0 + j;
        float* op = out + ((size_t)(b * 3) * HH + y) * WW + tx0 + i0;
        *(float4*)op = ov;
        *(float4*)(op + (size_t)HH * WW) = ov;
        *(float4*)(op + (size_t)2 * HH * WW) = ov;
    }
}

extern "C" void kernel_launch(void* const* d_in, const int* in_sizes, int n_in,
                              void* d_out, int out_size, void* d_ws, size_t ws_size,
                              hipStream_t stream) {
    const float* x = (const float*)d_in[0];
    float* out = (float*)d_out;
    dim3 grid(WW / TW, HH / TH, NB);
    dim3 block(256);
    hipLaunchKernelGGL(canny_fused_kernel, grid, block, 0, stream, x, out);
}

// Round 4
// 37.429 us; speedup vs baseline: 1.2848x; 1.0724x over previous
//
#include <hip/hip_runtime.h>
#include <math.h>

// Canny NMS magnitude extractor, fused + separable + vectorized + LDS-overlaid.
// x: [16,3,512,512] f32 -> out: [16,3,512,512] f32

#define HH 512
#define WW 512
#define NB 16
#define TH 32            // output tile rows (y)
#define TW 64            // output tile cols (x)
// gray tile: 40 rows (y: ty0-4..ty0+35) x 72 cols (x: tx0-4..tx0+67), stride 76
#define GH 40
#define GW 72
#define GS 76
// hblur: 40 rows x 68 cols (x: tx0-2..tx0+65), stride 68
#define HS 68
// vblur: 36 rows (y: ty0-2..ty0+33) x 68 cols, stride 68  -- overlays gray
#define BH 36
#define BS 68
// mag: 34 rows x 68 cols -- overlays hblur
// flags: 34 rows x 17 words (4 pixels/word, 4 bits used per byte)

__device__ __forceinline__ int reflect_i(int i, int n) {
    if (i < 0) i = -i;
    if (i >= n) i = 2 * n - 2 - i;
    return i;
}

__global__ __launch_bounds__(256, 6)
void canny_fused_kernel(const float* __restrict__ in, float* __restrict__ out) {
    const int tx0 = blockIdx.x * TW;
    const int ty0 = blockIdx.y * TH;
    const int b   = blockIdx.z;
    const int tid = threadIdx.x;

    __shared__ float sPool[6338];            // 25352 B -> 6 blocks/CU
    float*    sG = sPool;                    // 40*76 = 3040
    float*    sH = sPool + 3040;             // 40*68 = 2720
    float*    sB = sPool;                    // 36*68 = 2448, overlays gray
    float*    sM = sPool + 3040;             // 34*68 = 2312, overlays hblur
    unsigned* sF = (unsigned*)(sPool + 5760); // 34*17 = 578 words

    // Gaussian weights exactly as reference (f32 expf, f32-sum normalize)
    float g1[5];
    {
        float s = 0.f;
        #pragma unroll
        for (int i = 0; i < 5; ++i) {
            float a = (float)i - 2.0f;
            g1[i] = expf(-0.5f * a * a);
            s += g1[i];
        }
        #pragma unroll
        for (int i = 0; i < 5; ++i) g1[i] = g1[i] / s;
    }

    const float* inb = in + (size_t)b * 3 * HH * WW;

    // ---- P1: grayscale -> sG (reflect-mapped), float4 per thread -----------
    #pragma unroll
    for (int k = 0; k < 3; ++k) {
        int s = tid + k * 256;
        if (s < GH * (GW / 4)) {                 // 40*18 = 720
            int j = s / 18, q = s - j * 18;
            int y = reflect_i(ty0 - 4 + j, HH);
            int xs = tx0 - 4 + 4 * q;
            const float* p = inb + (size_t)y * WW;
            float4 gr;
            if (xs >= 0 && xs + 3 < WW) {
                float4 r = *(const float4*)(p + xs);
                float4 g = *(const float4*)(p + xs + HH * WW);
                float4 bl = *(const float4*)(p + xs + 2 * HH * WW);
                gr.x = r.x * 0.299f + g.x * 0.587f + bl.x * 0.114f;
                gr.y = r.y * 0.299f + g.y * 0.587f + bl.y * 0.114f;
                gr.z = r.z * 0.299f + g.z * 0.587f + bl.z * 0.114f;
                gr.w = r.w * 0.299f + g.w * 0.587f + bl.w * 0.114f;
            } else {
                float t[4];
                #pragma unroll
                for (int e = 0; e < 4; ++e) {
                    int xm = reflect_i(xs + e, WW);
                    t[e] = p[xm] * 0.299f + p[xm + HH * WW] * 0.587f
                         + p[xm + 2 * HH * WW] * 0.114f;
                }
                gr.x = t[0]; gr.y = t[1]; gr.z = t[2]; gr.w = t[3];
            }
            *(float4*)(sG + j * GS + 4 * q) = gr;
        }
    }
    __syncthreads();

    // ---- P2: horizontal gaussian, 4 outputs/thread -------------------------
    #pragma unroll
    for (int k = 0; k < 3; ++k) {
        int s = tid + k * 256;
        if (s < GH * 17) {                        // 680
            int j = s / 17, q = s - j * 17;
            int c0 = 4 * q;
            float4 a = *(const float4*)(sG + j * GS + c0);
            float4 bq = *(const float4*)(sG + j * GS + c0 + 4);
            float v0 = a.x, v1 = a.y, v2 = a.z, v3 = a.w;
            float v4 = bq.x, v5 = bq.y, v6 = bq.z, v7 = bq.w;
            float4 o;
            o.x = g1[0]*v0 + g1[1]*v1 + g1[2]*v2 + g1[3]*v3 + g1[4]*v4;
            o.y = g1[0]*v1 + g1[1]*v2 + g1[2]*v3 + g1[3]*v4 + g1[4]*v5;
            o.z = g1[0]*v2 + g1[1]*v3 + g1[2]*v4 + g1[3]*v5 + g1[4]*v6;
            o.w = g1[0]*v3 + g1[1]*v4 + g1[2]*v5 + g1[3]*v6 + g1[4]*v7;
            *(float4*)(sH + j * HS + c0) = o;
        }
    }
    __syncthreads();

    // ---- edge fixup: sobel replicate pad in x (blur(x<0)=blur(0) etc.) -----
    if (tx0 == 0) {
        if (tid < GH) {
            float v = sH[tid * HS + 2];
            sH[tid * HS + 0] = v;
            sH[tid * HS + 1] = v;
        }
        __syncthreads();
    }
    if (tx0 == WW - TW) {
        if (tid < GH) {
            float v = sH[tid * HS + 65];
            sH[tid * HS + 66] = v;
            sH[tid * HS + 67] = v;
        }
        __syncthreads();
    }

    // ---- P3: vertical gaussian (center-y clamped -> replicate pad in y) ----
    // Writes into sB (= gray space; gray is dead after P2).
    #pragma unroll
    for (int k = 0; k < 3; ++k) {
        int s = tid + k * 256;
        if (s < BH * 17) {                        // 612
            int r = s / 17, q = s - r * 17;
            int c0 = 4 * q;
            int yc = min(max(ty0 - 2 + r, 0), HH - 1);
            int rb = yc - ty0 + 2;                // htmp row base (taps rb..rb+4)
            float4 o = make_float4(0.f, 0.f, 0.f, 0.f);
            #pragma unroll
            for (int t = 0; t < 5; ++t) {
                float4 rw = *(const float4*)(sH + (rb + t) * HS + c0);
                o.x += g1[t] * rw.x;
                o.y += g1[t] * rw.y;
                o.z += g1[t] * rw.z;
                o.w += g1[t] * rw.w;
            }
            *(float4*)(sB + r * BS + c0) = o;
        }
    }
    __syncthreads();

    // ---- P4: sobel magnitude + packed direction flags ----------------------
    // Writes sM (= hblur space; hblur dead after P3) and byte-packed sF.
    #pragma unroll
    for (int k = 0; k < 3; ++k) {
        int s = tid + k * 256;
        if (s < 34 * 17) {                        // 578
            int m = s / 17, q = s - m * 17;
            int c0 = 4 * q;
            int c4 = (q == 16) ? 64 : c0 + 4;     // clamp (mag cols 66,67 unused)
            float R[3][8];
            #pragma unroll
            for (int r = 0; r < 3; ++r) {
                float4 a = *(const float4*)(sB + (m + r) * BS + c0);
                float4 bb = *(const float4*)(sB + (m + r) * BS + c4);
                R[r][0] = a.x;  R[r][1] = a.y;  R[r][2] = a.z;  R[r][3] = a.w;
                R[r][4] = bb.x; R[r][5] = bb.y; R[r][6] = bb.z; R[r][7] = bb.w;
            }
            int y = ty0 - 1 + m;
            bool yin = (y >= 0) && (y < HH);
            float mg[4]; unsigned pk = 0;
            #pragma unroll
            for (int li = 0; li < 4; ++li) {
                float b00 = R[0][li], b01 = R[0][li+1], b02 = R[0][li+2];
                float b10 = R[1][li],                   b12 = R[1][li+2];
                float b20 = R[2][li], b21 = R[2][li+1], b22 = R[2][li+2];
                float gx = ((((-b00 + b02) - 2.f * b10) + 2.f * b12) - b20) + b22;
                float gy = ((((-b00 - 2.f * b01) - b02) + b20) + 2.f * b21) + b22;
                int x = tx0 - 1 + c0 + li;
                bool inimg = yin && (x >= 0) && (x < WW);
                mg[li] = inimg ? sqrtf(gx * gx + gy * gy + 1e-6f) : 0.0f;
                float adx = fabsf(gx), ady = fabsf(gy);
                unsigned f = 0;
                f |= (ady <= 0.41421356237309503f * adx) ? 1u : 0u;  // horizontal
                f |= (ady >= 2.414213562373095f  * adx) ? 2u : 0u;   // vertical
                f |= (gy >= 0.f) ? 4u : 0u;
                f |= (gx >= 0.f) ? 8u : 0u;
                pk |= f << (8 * li);
            }
            float4 mv; mv.x = mg[0]; mv.y = mg[1]; mv.z = mg[2]; mv.w = mg[3];
            *(float4*)(sM + m * 68 + c0) = mv;
            sF[m * 17 + q] = pk;
        }
    }
    __syncthreads();

    // ---- P5: NMS select + clip + store x3 channels ------------------------
    #pragma unroll
    for (int k = 0; k < 2; ++k) {
        int s = tid + k * 256;                    // 512 exact
        int j = s >> 4, q = s & 15;
        int i0 = 4 * q;
        float W[3][6];
        #pragma unroll
        for (int r = 0; r < 3; ++r) {
            float4 a = *(const float4*)(sM + (j + r) * 68 + i0);
            float2 bb = *(const float2*)(sM + (j + r) * 68 + i0 + 4);
            W[r][0] = a.x; W[r][1] = a.y; W[r][2] = a.z; W[r][3] = a.w;
            W[r][4] = bb.x; W[r][5] = bb.y;
        }
        // flags for pixels (j+1, i0+1..i0+4): bytes i0+1..i0+4 of flag row j+1
        unsigned w0 = sF[(j + 1) * 17 + q];
        unsigned w1 = sF[(j + 1) * 17 + q + 1];
        unsigned packed = (w0 >> 8) | (w1 << 24);

        float o[4];
        #pragma unroll
        for (int li = 0; li < 4; ++li) {
            float mc = W[1][li + 1];
            unsigned f = (packed >> (8 * li)) & 0xffu;
            bool h  = (f & 1u) != 0u;
            bool v  = (f & 2u) != 0u;
            bool sy = (f & 4u) != 0u;
            bool sx = (f & 8u) != 0u;
            float p0 = v ? W[0][li+1] : (sx ? W[0][li+2] : W[0][li]);
            float p1 = v ? W[1][li+1] : (sx ? W[1][li+2] : W[1][li]);
            float p2 = v ? W[2][li+1] : (sx ? W[2][li+2] : W[2][li]);
            float pv = h ? p1 : (sy ? p2 : p0);
            float n0 = v ? W[0][li+1] : (sx ? W[0][li] : W[0][li+2]);
            float n1 = v ? W[1][li+1] : (sx ? W[1][li] : W[1][li+2]);
            float n2 = v ? W[2][li+1] : (sx ? W[2][li] : W[2][li+2]);
            float nv = h ? n1 : (sy ? n0 : n2);
            o[li] = (mc > fmaxf(pv, nv)) ? fminf(mc, 1.0f) : 0.0f;
        }
        float4 ov; ov.x = o[0]; ov.y = o[1]; ov.z = o[2]; ov.w = o[3];
        int y = ty0 + j;
        float* op = out + ((size_t)(b * 3) * HH + y) * WW + tx0 + i0;
        *(float4*)op = ov;
        *(float4*)(op + (size_t)HH * WW) = ov;
        *(float4*)(op + (size_t)2 * HH * WW) = ov;
    }
}

extern "C" void kernel_launch(void* const* d_in, const int* in_sizes, int n_in,
                              void* d_out, int out_size, void* d_ws, size_t ws_size,
                              hipStream_t stream) {
    const float* x = (const float*)d_in[0];
    float* out = (float*)d_out;
    dim3 grid(WW / TW, HH / TH, NB);
    dim3 block(256);
    hipLaunchKernelGGL(canny_fused_kernel, grid, block, 0, stream, x, out);
}